// Round 9
// baseline (118.154 us; speedup 1.0000x reference)
//
#include <hip/hip_runtime.h>
#include <hip/hip_bf16.h>

// out[b,d,r] = sum_c p[b,c] * softmax_d( x[b,:] @ W[:, c*8+d, r] + bias[c,d,r] )
// B=16384, F=128, C=8, R=64.  bf16 MFMA 32x32x16, fully fused.
//
// R18->R19: R18 (~33us fused) sits at 1.6x the 16x16x32 shape's 20.5us
// LDS-read floor (16B W per output, M=16 amortization).  The 32x32x16
// batch-in-cols mapping halves that (8B/output, N=32) and was numerically
// VERIFIED by R17 (passed, absmax 0.0078125); R17 lost only on (1) 16B
// stride-256B fragment stores (WRITE 91MB = 2.7x amp) and (2) ~3 waves/SIMD
// against an 8-deep serial MFMA chain.  R19 fixes both:
//  - 512thr/8wave blocks = 2 batch-groups x 4 w4-subchunks: block owns
//    64 b x 16 r x 8 d = complete 64B out lines.  Epilogue transposes O
//    through LDS ([d*16+r][66-pitch b] layout: scalar writes conflict-free,
//    reads ~8-way but one-shot) then stores fully-coalesced f32x4 lines.
//  - stage 32KB/c (8 frag x 4 w4s, each wave loads 4), ring-2 = 64KB ->
//    2 blocks/CU = 16 waves/CU = 4 independent MFMA chains per SIMD.
//  - R14-proven schedule verbatim: ONE barrier/c, stage(c+1) issued right
//    after it; w-major grid (XCD = g%8); LOG2E folded into wf/bias_r
//    (exp2 direct); bias_r as MFMA C-in; pT coalesced p loads.
// W-LDS-read per CU per c: 128KB (vs R14's 512KB).

#define F_DIM    128
#define NCOL     4096      // C*C*R
#define OUT_STRIDE 512     // C*R
#define LOG2E    1.44269504088896340736f

typedef __bf16 bf16x8 __attribute__((ext_vector_type(8)));
typedef float  f32x4  __attribute__((ext_vector_type(4)));
typedef float  f32x16 __attribute__((ext_vector_type(16)));

#define AS1(p) ((const __attribute__((address_space(1))) unsigned int*)(p))
#define AS3(p) ((__attribute__((address_space(3))) unsigned int*)(p))

// ---------------------------------------------------------------------------
// Prepass (VERIFIED in R17): W fp32 (128 x 4096) -> bf16 A-operand fragments
// for mfma_f32_32x32x16_bf16, pre-scaled by log2(e).
// Fragment gf = (c*16 + w4)*8 + kst: lane l holds A[row m = l&31]
// [k = kst*16 + (l>>5)*8 + j], row m -> col n = c*512 + (m&7)*64 + w4*4 +
// (m>>3)  (d = m&7, rr = m>>3).  Also pT[c][b] = p[b][c] and
// bias_r[(c*16+w4)*32 + m] = bias[c][m&7][w4*4 + m>>3] * log2e.
// ---------------------------------------------------------------------------
__global__ void wconv_kernel(const float* __restrict__ W,
                             const float* __restrict__ p,
                             const float* __restrict__ bias,
                             __bf16* __restrict__ wf,
                             float* __restrict__ pT,
                             float* __restrict__ bias_r) {
    int f    = blockIdx.x * 256 + threadIdx.x;  // 0..65535
    int lane = f & 63;
    int gf   = f >> 6;          // fragment id 0..1023
    int kst  = gf & 7;
    int w4   = (gf >> 3) & 15;
    int c    = gf >> 7;
    int m    = lane & 31;
    int kbase = kst * 16 + (lane >> 5) * 8;
    int n     = c * 512 + (m & 7) * 64 + w4 * 4 + (m >> 3);
    bf16x8 frag;
#pragma unroll
    for (int j = 0; j < 8; ++j)
        frag[j] = (__bf16)(W[(kbase + j) * NCOL + n] * LOG2E);
    *(bf16x8*)(wf + (size_t)f * 8) = frag;

#pragma unroll
    for (int u = f; u < 131072; u += 65536)
        pT[u] = p[(size_t)(u & 16383) * 8 + (u >> 14)];

    if (f < 4096) {
        int cc = f >> 9, ww4 = (f >> 5) & 15, mm = f & 31;
        bias_r[f] = bias[cc * 512 + (mm & 7) * 64 + ww4 * 4 + (mm >> 3)] * LOG2E;
    }
}

// ---------------------------------------------------------------------------
// Fused GEMM + bias + softmax(d) + p-contraction.  mfma 32x32x16.
// Block: 512 thr (8 waves) = 2 batch-groups (bg) x 4 w4-subchunks (w4s).
// Block covers 64 batch x one 16-r chunk (w16) x all 8 d.  Wave (bg,w4s):
// 32 batch cols, 32 A-rows (8 d x 4 rr at w4 = w16*4+w4s).  Per c: 32
// fragments (4 w4s x 8 kst, 32 KB) ring-2 staged (wave stages its w4s's
// kst = bg*4..+3); x in registers as B-operand (xfr[8]).  Softmax: per r2
// 3 in-lane adds + 1 shfl_xor(32); C-in = bias_r.  Epilogue: O -> LDS
// transpose -> coalesced full-line f32x4 stores.
// ---------------------------------------------------------------------------
__global__ __launch_bounds__(512, 4)
void fused_kernel(const float* __restrict__ x, const float* __restrict__ pT,
                  const float* __restrict__ bias_r, const __bf16* __restrict__ wf,
                  float* __restrict__ out) {
    __shared__ __align__(16) char lds[65536];   // ring: 2 x 32 KB; epilogue reuse

    const int lane = threadIdx.x & 63;
    const int ww   = threadIdx.x >> 6;   // wave 0..7
    const int bg   = ww >> 2;            // batch-group 0..1
    const int w4s  = ww & 3;             // w4 subchunk 0..3
    const int l31  = lane & 31;          // batch col within wave
    const int h    = lane >> 5;          // half: +4 to C/D row
    const int w16  = blockIdx.x >> 8;    // 16-r chunk 0..3 (w-major)
    const int g    = blockIdx.x & 255;   // batch group (XCD = g%8)
    const int b0   = g * 64 + bg * 32;
    const int w4   = w16 * 4 + w4s;

    // ---- prologue: stage c=0 into ring slot 0 -----------------------------
    // wave (bg,w4s) stages fragments (w4s, kst = bg*4 + s), s=0..3.
#pragma unroll
    for (int s = 0; s < 4; ++s) {
        int kst = bg * 4 + s;
        int gfr = w4 * 8 + kst;          // c = 0
        __builtin_amdgcn_global_load_lds(
            AS1((const char*)wf + (size_t)gfr * 1024 + lane * 16),
            AS3(lds + (w4s * 8 + kst) * 1024), 16, 0, 0);
    }

    // x B-fragments: xfr[kst][j] = x_bf16[b0 + l31][kst*16 + h*8 + j]
    bf16x8 xfr[8];
    {
        const float* xr = x + (size_t)(b0 + l31) * F_DIM + h * 8;
#pragma unroll
        for (int kst = 0; kst < 8; ++kst) {
            float4 lo = *(const float4*)(xr + kst * 16);
            float4 hi = *(const float4*)(xr + kst * 16 + 4);
            bf16x8 fr;
            fr[0] = (__bf16)lo.x; fr[1] = (__bf16)lo.y;
            fr[2] = (__bf16)lo.z; fr[3] = (__bf16)lo.w;
            fr[4] = (__bf16)hi.x; fr[5] = (__bf16)hi.y;
            fr[6] = (__bf16)hi.z; fr[7] = (__bf16)hi.w;
            xfr[kst] = fr;
        }
    }

    float O[16] = {};   // [reg] accumulator over c; reg i -> (d=(i&3)+4h, rr=i>>2)

#pragma unroll 1
    for (int c = 0; c < 8; ++c) {
        // barrier: stage(c) landed (issued a full phase ago) AND all waves
        // done reading ring[(c+1)&1] from iteration c-1.
        __syncthreads();

        // ---- issue stage(c+1) into the other ring slot (hides under compute)
        if (c < 7) {
            char* dst = lds + ((c + 1) & 1) * 32768;
#pragma unroll
            for (int s = 0; s < 4; ++s) {
                int kst = bg * 4 + s;
                int gfr = ((c + 1) * 16 + w4) * 8 + kst;
                __builtin_amdgcn_global_load_lds(
                    AS1((const char*)wf + (size_t)gfr * 1024 + lane * 16),
                    AS3(dst + (w4s * 8 + kst) * 1024), 16, 0, 0);
            }
        }

        // ---- p (coalesced) and bias (2x f32x4), issued pre-MFMA -----------
        float pv = pT[(size_t)c * 16384 + b0 + l31];

        f32x4 bvl[4];
#pragma unroll
        for (int r2 = 0; r2 < 4; ++r2)
            bvl[r2] = *(const f32x4*)(bias_r + (c * 16 + w4) * 32 + r2 * 8 + h * 4);

        // C-in = bias_r (row m = (i&3) + 8*(i>>2) + 4h; col-invariant)
        f32x16 acc;
#pragma unroll
        for (int i = 0; i < 16; ++i)
            acc[i] = bvl[i >> 2][i & 3];

        const char* buf = lds + (c & 1) * 32768;
#pragma unroll
        for (int kst = 0; kst < 8; ++kst) {
            bf16x8 af = *(const bf16x8*)(buf + (w4s * 8 + kst) * 1024 + lane * 16);
            acc = __builtin_amdgcn_mfma_f32_32x32x16_bf16(af, xfr[kst], acc, 0, 0, 0);
        }

        // ---- softmax over d (= (i&3)+4h) + p-weighted accumulate ----------
#pragma unroll
        for (int r2 = 0; r2 < 4; ++r2) {
            float e0 = __builtin_amdgcn_exp2f(acc[r2 * 4 + 0]);
            float e1 = __builtin_amdgcn_exp2f(acc[r2 * 4 + 1]);
            float e2 = __builtin_amdgcn_exp2f(acc[r2 * 4 + 2]);
            float e3 = __builtin_amdgcn_exp2f(acc[r2 * 4 + 3]);
            float s4 = (e0 + e1) + (e2 + e3);       // this half's 4 d's
            float s8 = s4 + __shfl_xor(s4, 32, 64); // + other half's 4 d's
            float scale = pv * __builtin_amdgcn_rcpf(s8);
            O[r2 * 4 + 0] = __builtin_fmaf(e0, scale, O[r2 * 4 + 0]);
            O[r2 * 4 + 1] = __builtin_fmaf(e1, scale, O[r2 * 4 + 1]);
            O[r2 * 4 + 2] = __builtin_fmaf(e2, scale, O[r2 * 4 + 2]);
            O[r2 * 4 + 3] = __builtin_fmaf(e3, scale, O[r2 * 4 + 3]);
        }
    }

    // ======================= epilogue: transpose + store ===================
    // All waves must finish ring reads before LDS is reused.
    __syncthreads();

    // write: lane value i -> (b = bg*32+l31, d = (i&3)+4h, rloc = w4s*4 + (i>>2))
    // LDS layout: [dr = d*16 + rloc][pitch 66: b 0..63]  (33792 B).
    // banks: (dr*66 + b) % 32 = (2dr + b) % 32 -> lanes of a half distinct,
    // halves pairwise 2-way (free).
    float* L = (float*)lds;
#pragma unroll
    for (int i = 0; i < 16; ++i) {
        int d    = (i & 3) + 4 * h;
        int rloc = w4s * 4 + (i >> 2);
        L[(d * 16 + rloc) * 66 + bg * 32 + l31] = O[i];
    }
    __syncthreads();

    // read + store: thread t covers 4 f32x4 chunks; consecutive t ->
    // consecutive 16B of out -> perfectly coalesced full 64B lines.
#pragma unroll
    for (int j = 0; j < 4; ++j) {
        int linear = threadIdx.x * 4 + j * 2048;   // 0..8188, %4 == 0
        int bq = linear >> 7;                      // 0..63
        int dr = linear & 127;                     // d*16 + rloc, %4 == 0
        f32x4 v;
#pragma unroll
        for (int k = 0; k < 4; ++k)
            v[k] = L[(dr + k) * 66 + bq];
        *(f32x4*)(out + (size_t)(g * 64 + bq) * OUT_STRIDE
                      + (dr >> 4) * 64 + w16 * 16 + (dr & 15)) = v;
    }
}

extern "C" void kernel_launch(void* const* d_in, const int* in_sizes, int n_in,
                              void* d_out, int out_size, void* d_ws, size_t ws_size,
                              hipStream_t stream) {
    const float* x    = (const float*)d_in[0];   // (16384, 128)
    const float* p    = (const float*)d_in[1];   // (16384, 8)
    const float* W    = (const float*)d_in[2];   // (128, 64, 64)
    const float* bias = (const float*)d_in[3];   // (8, 8, 64)
    float* out = (float*)d_out;                  // (16384, 8, 64)
    __bf16* wf     = (__bf16*)d_ws;                          // 1 MB fragments
    float*  pT     = (float*)((char*)d_ws + (1 << 20));      // 512 KB p^T
    float*  bias_r = (float*)((char*)d_ws + (1 << 20) + (512 << 10)); // 16 KB

    wconv_kernel<<<dim3(256), dim3(256), 0, stream>>>(W, p, bias, wf, pT, bias_r);
    fused_kernel<<<dim3(1024), dim3(512), 0, stream>>>(x, pT, bias_r, wf, out);
}

// Round 10
// 114.589 us; speedup vs baseline: 1.0311x; 1.0311x over previous
//
#include <hip/hip_runtime.h>
#include <hip/hip_bf16.h>

// out[b,d,r] = sum_c p[b,c] * softmax_d( x[b,:] @ W[:, c*8+d, r] + bias[c,d,r] )
// B=16384, F=128, C=8, R=64.  bf16 MFMA 16x16x32, fully fused.
//
// R19->R20: 32x32x16 closed for good (R17 53.6us, R19 52.7us: one serial
// 8-MFMA chain per wave, no ILP).  R18 (33us fused) is LDS-read-pipe bound:
// 512KB/CU/c through the 128B/cyc LDS pipe (~6kcyc) while the 64B/cyc
// TA/L1 pipe sits near idle.  R20 SPLITS the B-fragment traffic across
// both pipes instead of shrinking it (every shrink attempt -- m=2, N=32 --
// traded away occupancy or ILP and lost):
//  - d=0..5 staged to LDS as before (24KB/c, ring 2x24KB = 48KB/block);
//  - d=6,7 read per-wave DIRECTLY from wf (8x global_load_dwordx4, hoisted
//    right after the barrier, consumed last in the d-loop).  Block-shared
//    16KB/c -> L1-resident (2 blocks x 16KB = L1 size; wf is L3-resident).
// New per-CU/c balance: LDS 384KB ~3kcyc || TA 176KB ~2.75kcyc -> ~10us
// floor (was 20.5).  Regs ~90 VGPR + 32 AGPR < 128 combined, 16 waves/CU.
// Everything else R18-verbatim: d-outer MFMA (8 independent chains,
// in-place exp2 overlap), LOG2E folded in prepass (exp2 direct), biasT
// C-in (2 f32x4), ONE barrier/c + stage(c+1) right after, w-major grid
// (XCD = g%8), in-lane softmax (zero shuffles), full 64B-line stores.

#define F_DIM    128
#define NCOL     4096      // C*C*R
#define OUT_STRIDE 512     // C*R
#define LOG2E    1.44269504088896340736f

typedef __bf16 bf16x8 __attribute__((ext_vector_type(8)));
typedef float  f32x4  __attribute__((ext_vector_type(4)));

#define AS1(p) ((const __attribute__((address_space(1))) unsigned int*)(p))
#define AS3(p) ((__attribute__((address_space(3))) unsigned int*)(p))

// ---------------------------------------------------------------------------
// Prepass (R18-verbatim): W fp32 (128 x 4096 row-major) -> bf16 MFMA
// B-fragments, PRE-SCALED by log2(e).  Tile t = (c*8+d)*4 + w covers cols
// t*16..t*16+16; fragment (t,kk) holds k = kk*32 + (lane>>4)*8 + j,
// n = t*16 + (lane&15), at wf[(t*4+kk)*512].
// Also emits biasT[(c*64 + r)*8 + d] = bias[c][d][r] * log2e  (16 KB).
// ---------------------------------------------------------------------------
__global__ void wconv_kernel(const float* __restrict__ W,
                             const float* __restrict__ bias,
                             __bf16* __restrict__ wf,
                             float* __restrict__ biasT) {
    int f    = blockIdx.x * 256 + threadIdx.x;  // 0..65535
    int lane = f & 63;
    int tkk  = f >> 6;
    int t    = tkk >> 2;
    int kk   = tkk & 3;
    int kbase = kk * 32 + (lane >> 4) * 8;
    int n     = t * 16 + (lane & 15);
    bf16x8 frag;
#pragma unroll
    for (int j = 0; j < 8; ++j)
        frag[j] = (__bf16)(W[(kbase + j) * NCOL + n] * LOG2E);
    *(bf16x8*)(wf + (size_t)f * 8) = frag;

    if (f < 4096) {   // biasT: [c][r][d]
        int c = f >> 9, r = (f >> 3) & 63, d = f & 7;
        biasT[f] = bias[(c * 8 + d) * 64 + r] * LOG2E;
    }
}

// ---------------------------------------------------------------------------
// Fused GEMM + bias + softmax(d) + p-contraction.
// Block: 512 thr (8 waves), 128 batch rows, one 16-r chunk w = blockIdx>>7.
// Wave ww owns rows b0..b0+16.  Per c: d0-5's 24 fragments (24 KB) ring-2
// staged (wave ww stages fragments ww*3..ww*3+2); d6-7's 8 fragments loaded
// per-wave straight from wf (L1-shared).  d-OUTER mfma: 8 independent
// 4-chains; in-place exp2 overlaps later d's reads.  Softmax in-lane
// (7-add tree, 1 rcp, 8 fma per jj).  C-in = biasT (2 f32x4 loads).
// C/D layout: col=lane&15 -> r, row=quad*4+jj -> batch row.
// ---------------------------------------------------------------------------
__global__ __launch_bounds__(512, 4)
void fused_kernel(const float* __restrict__ x, const float* __restrict__ p,
                  const float* __restrict__ biasT, const __bf16* __restrict__ wf,
                  float* __restrict__ out) {
    __shared__ __align__(16) char lds[49152];   // 2 x (24 fragments = 24 KB)

    const int lane = threadIdx.x & 63;
    const int ww   = threadIdx.x >> 6;   // wave 0..7 = m-tile
    const int quad = lane >> 4;
    const int l15  = lane & 15;
    const int w    = blockIdx.x >> 7;    // r-chunk 0..3 (w-major: XCD = g%8)
    const int g    = blockIdx.x & 127;   // row-group
    const int b0   = g * 128 + ww * 16;

    // ---- prologue: stage c=0, d0-5 into ring slot 0 (3 frags per wave) ----
#pragma unroll
    for (int s = 0; s < 3; ++s) {
        int fi = ww * 3 + s;             // 0..23
        int d  = fi >> 2;
        int kk = fi & 3;
        int gf = (d * 4 + w) * 4 + kk;   // c = 0
        __builtin_amdgcn_global_load_lds(
            AS1(wf + (size_t)gf * 512 + lane * 8),
            AS3(lds + fi * 1024), 16, 0, 0);
    }

    // A fragments: afr[kk][j] = x_bf16[b0+l15][kk*32 + quad*8 + j]
    bf16x8 afr[4];
    {
        const float* xr = x + (size_t)(b0 + l15) * F_DIM + quad * 8;
#pragma unroll
        for (int kk = 0; kk < 4; ++kk) {
            float4 lo = *(const float4*)(xr + kk * 32);
            float4 hi = *(const float4*)(xr + kk * 32 + 4);
            bf16x8 f;
            f[0] = (__bf16)lo.x; f[1] = (__bf16)lo.y;
            f[2] = (__bf16)lo.z; f[3] = (__bf16)lo.w;
            f[4] = (__bf16)hi.x; f[5] = (__bf16)hi.y;
            f[6] = (__bf16)hi.z; f[7] = (__bf16)hi.w;
            afr[kk] = f;
        }
    }

    float O[8][4] = {};   // [d][jj] output accumulator over c

#pragma unroll 1
    for (int c = 0; c < 8; ++c) {
        // barrier: stage(c) landed (its loads had the whole previous compute
        // phase in flight) AND all waves done reading ring[(c+1)&1].
        __syncthreads();

        // ---- d6-7 direct loads: issue FIRST (consumed last in the d-loop) -
        bf16x8 g6[4], g7[4];
        {
            const __bf16* w6 = wf + (size_t)(((c * 8 + 6) * 4 + w) * 4) * 512 + lane * 8;
            const __bf16* w7 = w6 + 16 * 512;
#pragma unroll
            for (int kk = 0; kk < 4; ++kk) {
                g6[kk] = *(const bf16x8*)(w6 + kk * 512);
                g7[kk] = *(const bf16x8*)(w7 + kk * 512);
            }
        }

        // ---- issue stage(c+1) d0-5 into the other ring slot ---------------
        if (c < 7) {
            char* dst = lds + ((c + 1) & 1) * 24576;
#pragma unroll
            for (int s = 0; s < 3; ++s) {
                int fi = ww * 3 + s;
                int d  = fi >> 2;
                int kk = fi & 3;
                int gf = (((c + 1) * 8 + d) * 4 + w) * 4 + kk;
                __builtin_amdgcn_global_load_lds(
                    AS1(wf + (size_t)gf * 512 + lane * 8),
                    AS3(dst + fi * 1024), 16, 0, 0);
            }
        }

        // ---- p and bias loads issued before MFMAs -------------------------
        float pvv[4];
#pragma unroll
        for (int jj = 0; jj < 4; ++jj)
            pvv[jj] = p[(size_t)(b0 + quad * 4 + jj) * 8 + c];

        f32x4 bv0 = *(const f32x4*)(biasT + (c * 64 + w * 16 + l15) * 8);
        f32x4 bv1 = *(const f32x4*)(biasT + (c * 64 + w * 16 + l15) * 8 + 4);

        // ---- d-outer MFMA: d0-5 from LDS, d6-7 from registers -------------
        const char* buf = lds + (c & 1) * 24576;
        f32x4 acc[8];
#pragma unroll
        for (int d = 0; d < 6; ++d) {
            float bvd = (d < 4) ? bv0[d & 3] : bv1[d & 3];
            f32x4 a = {bvd, bvd, bvd, bvd};   // C-in = bias (row-invariant)
#pragma unroll
            for (int kk = 0; kk < 4; ++kk) {
                bf16x8 bfr = *(const bf16x8*)(buf + (d * 4 + kk) * 1024 + lane * 16);
                a = __builtin_amdgcn_mfma_f32_16x16x32_bf16(afr[kk], bfr, a, 0, 0, 0);
            }
            acc[d] = a;
        }
        {
            f32x4 a6 = {bv1[2], bv1[2], bv1[2], bv1[2]};
            f32x4 a7 = {bv1[3], bv1[3], bv1[3], bv1[3]};
#pragma unroll
            for (int kk = 0; kk < 4; ++kk) {
                a6 = __builtin_amdgcn_mfma_f32_16x16x32_bf16(afr[kk], g6[kk], a6, 0, 0, 0);
                a7 = __builtin_amdgcn_mfma_f32_16x16x32_bf16(afr[kk], g7[kk], a7, 0, 0, 0);
            }
            acc[6] = a6;
            acc[7] = a7;
        }

        // ---- in-place exp2 (interleaves under later d's reads) ------------
#pragma unroll
        for (int d = 0; d < 8; ++d)
#pragma unroll
            for (int jj = 0; jj < 4; ++jj)
                acc[d][jj] = __builtin_amdgcn_exp2f(acc[d][jj]);

        // ---- softmax denominator + p-weighted accumulate ------------------
#pragma unroll
        for (int jj = 0; jj < 4; ++jj) {
            float s01 = acc[0][jj] + acc[1][jj], s23 = acc[2][jj] + acc[3][jj];
            float s45 = acc[4][jj] + acc[5][jj], s67 = acc[6][jj] + acc[7][jj];
            float s = (s01 + s23) + (s45 + s67);
            float scale = pvv[jj] * __builtin_amdgcn_rcpf(s);
#pragma unroll
            for (int d = 0; d < 8; ++d)
                O[d][jj] = __builtin_fmaf(acc[d][jj], scale, O[d][jj]);
        }
        // no second barrier: next iteration's __syncthreads covers the
        // write-after-read hazard on ring[(c+1)&1].
    }

    // ---- stores: out[b, d*64 + w*16 + l15] — 64B per quad, full lines -----
#pragma unroll
    for (int jj = 0; jj < 4; ++jj) {
        float* orow = out + (size_t)(b0 + quad * 4 + jj) * OUT_STRIDE + w * 16 + l15;
#pragma unroll
        for (int d = 0; d < 8; ++d)
            orow[d * 64] = O[d][jj];
    }
}

extern "C" void kernel_launch(void* const* d_in, const int* in_sizes, int n_in,
                              void* d_out, int out_size, void* d_ws, size_t ws_size,
                              hipStream_t stream) {
    const float* x    = (const float*)d_in[0];   // (16384, 128)
    const float* p    = (const float*)d_in[1];   // (16384, 8)
    const float* W    = (const float*)d_in[2];   // (128, 64, 64)
    const float* bias = (const float*)d_in[3];   // (8, 8, 64)
    float* out = (float*)d_out;                  // (16384, 8, 64)
    __bf16* wf    = (__bf16*)d_ws;               // 1 MB bf16 fragments
    float*  biasT = (float*)((char*)d_ws + (1 << 20));  // 16 KB scaled bias

    wconv_kernel<<<dim3(256), dim3(256), 0, stream>>>(W, bias, wf, biasT);
    fused_kernel<<<dim3(512), dim3(512), 0, stream>>>(x, p, biasT, wf, out);
}

// Round 11
// 98.465 us; speedup vs baseline: 1.2000x; 1.1638x over previous
//
#include <hip/hip_runtime.h>
#include <hip/hip_bf16.h>

// out[b,d,r] = sum_c p[b,c] * softmax_d( x[b,:] @ W[:, c*8+d, r] + bias[c,d,r] )
// B=16384, F=128, C=8, R=64.  bf16 MFMA 16x16x32, fully fused.
//
// R20->R21: R20's TA-pipe split regressed (51.6us: mid-loop vmcnt FIFO
// serialization + 32 extra live VGPR); closed -- all B-traffic stays on
// LDS.  R21 = champion R18 + three surgical changes, no structure change:
//  1. exp2 fused INTO the d-loop (right after acc[d]'s last MFMA): each
//     wave's softmax VALU interleaves with its own later d's ds_reads,
//     shrinking the per-c all-waves softmax tail (~38% LDS-idle source).
//  2. p/biasT loads issued BEFORE stage(c+1): the pre-MFMA vmcnt wait
//     (bias is C-in) provably leaves the stage loads in flight.
//  3. Nontemporal O stores: avoids the 2-blocks-per-128B-line L2 merge
//     race (WRITE_SIZE family evidence: 41-91MB for 33.5MB output).
// Proven-and-kept: 512thr/8wave blocks, grid 512 (2 blk/CU, 16 waves/CU),
// 2x32KB LDS ring, ONE barrier/c, d-outer MFMA (8 independent chains),
// LOG2E folded in prepass (exp2 direct), biasT C-in, w-major grid
// (XCD = g%8), in-lane softmax (zero shuffles), 64B-line stores.

#define F_DIM    128
#define NCOL     4096      // C*C*R
#define OUT_STRIDE 512     // C*R
#define LOG2E    1.44269504088896340736f

typedef __bf16 bf16x8 __attribute__((ext_vector_type(8)));
typedef float  f32x4  __attribute__((ext_vector_type(4)));

#define AS1(p) ((const __attribute__((address_space(1))) unsigned int*)(p))
#define AS3(p) ((__attribute__((address_space(3))) unsigned int*)(p))

// ---------------------------------------------------------------------------
// Prepass (R18-verbatim): W fp32 (128 x 4096 row-major) -> bf16 MFMA
// B-fragments, PRE-SCALED by log2(e).  Tile t = (c*8+d)*4 + w covers cols
// t*16..t*16+16; fragment (t,kk) holds k = kk*32 + (lane>>4)*8 + j,
// n = t*16 + (lane&15), at wf[(t*4+kk)*512].
// Also emits biasT[(c*64 + r)*8 + d] = bias[c][d][r] * log2e  (16 KB).
// ---------------------------------------------------------------------------
__global__ void wconv_kernel(const float* __restrict__ W,
                             const float* __restrict__ bias,
                             __bf16* __restrict__ wf,
                             float* __restrict__ biasT) {
    int f    = blockIdx.x * 256 + threadIdx.x;  // 0..65535
    int lane = f & 63;
    int tkk  = f >> 6;
    int t    = tkk >> 2;
    int kk   = tkk & 3;
    int kbase = kk * 32 + (lane >> 4) * 8;
    int n     = t * 16 + (lane & 15);
    bf16x8 frag;
#pragma unroll
    for (int j = 0; j < 8; ++j)
        frag[j] = (__bf16)(W[(kbase + j) * NCOL + n] * LOG2E);
    *(bf16x8*)(wf + (size_t)f * 8) = frag;

    if (f < 4096) {   // biasT: [c][r][d]
        int c = f >> 9, r = (f >> 3) & 63, d = f & 7;
        biasT[f] = bias[(c * 8 + d) * 64 + r] * LOG2E;
    }
}

// ---------------------------------------------------------------------------
// Fused GEMM + bias + softmax(d) + p-contraction.
// Block: 512 thr (8 waves), 128 batch rows, one 16-r chunk w = blockIdx>>7.
// Wave ww owns rows b0..b0+16.  Per c: 32 fragments (8 d x 4 kk, 32 KB)
// double-buffer-staged (wave ww stages d=ww's 4 kk frags); each wave reads
// all 32 (block-shared).  d-OUTER mfma with exp2 fused per-d.  Softmax
// in-lane (7-add tree, 1 rcp, 8 fma per jj).  C-in = biasT (2 f32x4).
// C/D layout: col=lane&15 -> r, row=quad*4+jj -> batch row.
// ---------------------------------------------------------------------------
__global__ __launch_bounds__(512, 4)
void fused_kernel(const float* __restrict__ x, const float* __restrict__ p,
                  const float* __restrict__ biasT, const __bf16* __restrict__ wf,
                  float* __restrict__ out) {
    __shared__ __align__(16) char lds[65536];   // 2 x (32 fragments = 32 KB)

    const int lane = threadIdx.x & 63;
    const int ww   = threadIdx.x >> 6;   // wave 0..7 = m-tile, also staged d
    const int quad = lane >> 4;
    const int l15  = lane & 15;
    const int w    = blockIdx.x >> 7;    // r-chunk 0..3 (w-major: XCD = g%8)
    const int g    = blockIdx.x & 127;   // row-group
    const int b0   = g * 128 + ww * 16;

    // ---- prologue: stage c=0 into buffer 0 (wave ww stages d=ww) ----------
    {
        const __bf16* src = wf + (size_t)((ww * 4 + w) * 4) * 512 + lane * 8;
#pragma unroll
        for (int kk = 0; kk < 4; ++kk)
            __builtin_amdgcn_global_load_lds(
                AS1(src + kk * 512),
                AS3(lds + (ww * 4 + kk) * 1024), 16, 0, 0);
    }

    // A fragments: afr[kk][j] = x_bf16[b0+l15][kk*32 + quad*8 + j]
    bf16x8 afr[4];
    {
        const float* xr = x + (size_t)(b0 + l15) * F_DIM + quad * 8;
#pragma unroll
        for (int kk = 0; kk < 4; ++kk) {
            float4 lo = *(const float4*)(xr + kk * 32);
            float4 hi = *(const float4*)(xr + kk * 32 + 4);
            bf16x8 f;
            f[0] = (__bf16)lo.x; f[1] = (__bf16)lo.y;
            f[2] = (__bf16)lo.z; f[3] = (__bf16)lo.w;
            f[4] = (__bf16)hi.x; f[5] = (__bf16)hi.y;
            f[6] = (__bf16)hi.z; f[7] = (__bf16)hi.w;
            afr[kk] = f;
        }
    }

    float O[8][4] = {};   // [d][jj] output accumulator over c

#pragma unroll 1
    for (int c = 0; c < 8; ++c) {
        // barrier: stage(c) landed (its loads had the whole previous compute
        // phase in flight) AND all waves done reading buf[(c+1)&1].
        __syncthreads();

        // ---- p and biasT FIRST: the pre-MFMA vmcnt wait for these leaves
        // the stage(c+1) loads (issued after) in flight. ---------------------
        float pvv[4];
#pragma unroll
        for (int jj = 0; jj < 4; ++jj)
            pvv[jj] = p[(size_t)(b0 + quad * 4 + jj) * 8 + c];

        f32x4 bv0 = *(const f32x4*)(biasT + (c * 64 + w * 16 + l15) * 8);
        f32x4 bv1 = *(const f32x4*)(biasT + (c * 64 + w * 16 + l15) * 8 + 4);

        // ---- issue stage(c+1) into the other buffer (hidden under compute)
        if (c < 7) {
            const __bf16* src =
                wf + (size_t)((((c + 1) * 8 + ww) * 4 + w) * 4) * 512 + lane * 8;
            char* dst = lds + ((c + 1) & 1) * 32768;
#pragma unroll
            for (int kk = 0; kk < 4; ++kk)
                __builtin_amdgcn_global_load_lds(
                    AS1(src + kk * 512),
                    AS3(dst + (ww * 4 + kk) * 1024), 16, 0, 0);
        }

        // ---- d-outer MFMA with exp2 fused per d: 8 independent 4-chains;
        // exp2(acc[d]) issues right after acc[d]'s last MFMA and interleaves
        // with d+1..7's ds_reads (keeps the LDS pipe fed through softmax). --
        const char* buf = lds + (c & 1) * 32768;
        f32x4 acc[8];
#pragma unroll
        for (int d = 0; d < 8; ++d) {
            float bvd = (d < 4) ? bv0[d & 3] : bv1[d & 3];
            f32x4 a = {bvd, bvd, bvd, bvd};   // C-in = bias (row-invariant)
#pragma unroll
            for (int kk = 0; kk < 4; ++kk) {
                bf16x8 bfr = *(const bf16x8*)(buf + (d * 4 + kk) * 1024 + lane * 16);
                a = __builtin_amdgcn_mfma_f32_16x16x32_bf16(afr[kk], bfr, a, 0, 0, 0);
            }
#pragma unroll
            for (int jj = 0; jj < 4; ++jj)
                a[jj] = __builtin_amdgcn_exp2f(a[jj]);
            acc[d] = a;
        }

        // ---- softmax denominator + p-weighted accumulate ------------------
#pragma unroll
        for (int jj = 0; jj < 4; ++jj) {
            float s01 = acc[0][jj] + acc[1][jj], s23 = acc[2][jj] + acc[3][jj];
            float s45 = acc[4][jj] + acc[5][jj], s67 = acc[6][jj] + acc[7][jj];
            float s = (s01 + s23) + (s45 + s67);
            float scale = pvv[jj] * __builtin_amdgcn_rcpf(s);
#pragma unroll
            for (int d = 0; d < 8; ++d)
                O[d][jj] = __builtin_fmaf(acc[d][jj], scale, O[d][jj]);
        }
        // no second barrier: next iteration's __syncthreads covers the
        // write-after-read hazard on buf[(c+1)&1].
    }

    // ---- stores: out[b, d*64 + w*16 + l15] — 64B per quad, nontemporal ----
#pragma unroll
    for (int jj = 0; jj < 4; ++jj) {
        float* orow = out + (size_t)(b0 + quad * 4 + jj) * OUT_STRIDE + w * 16 + l15;
#pragma unroll
        for (int d = 0; d < 8; ++d)
            __builtin_nontemporal_store(O[d][jj], orow + d * 64);
    }
}

extern "C" void kernel_launch(void* const* d_in, const int* in_sizes, int n_in,
                              void* d_out, int out_size, void* d_ws, size_t ws_size,
                              hipStream_t stream) {
    const float* x    = (const float*)d_in[0];   // (16384, 128)
    const float* p    = (const float*)d_in[1];   // (16384, 8)
    const float* W    = (const float*)d_in[2];   // (128, 64, 64)
    const float* bias = (const float*)d_in[3];   // (8, 8, 64)
    float* out = (float*)d_out;                  // (16384, 8, 64)
    __bf16* wf    = (__bf16*)d_ws;               // 1 MB bf16 fragments
    float*  biasT = (float*)((char*)d_ws + (1 << 20));  // 16 KB scaled bias

    wconv_kernel<<<dim3(256), dim3(256), 0, stream>>>(W, bias, wf, biasT);
    fused_kernel<<<dim3(512), dim3(512), 0, stream>>>(x, p, biasT, wf, out);
}